// Round 5
// baseline (1790.157 us; speedup 1.0000x reference)
//
#include <hip/hip_runtime.h>
#include <hip/hip_bf16.h>

#define N_NODES   50000
#define N_REL     16
#define HID       128
#define N_EDGES   1600000
#define N_TILES   3125          // N_NODES/16
#define N_BINS    800000        // N_TILES*256
#define N_SCANBLK 782           // ceil(N_BINS/1024)
#define N_MBLK    1563          // ceil(3125/2) tile-pairs (M=32 per block)
#define BS_FRAGS  544           // (16 rel + root)*4 kk * 8 cb frags per layer
#define BS_LAYER  278528        // BS_FRAGS * 512 ushorts

typedef unsigned short ushort_t;
typedef __attribute__((ext_vector_type(8))) short short8;
typedef __attribute__((ext_vector_type(4))) float f32x4;

union BF2U { __hip_bfloat162 h; unsigned u; };

__device__ __forceinline__ unsigned pack_bf16_2(float x, float y) {
  BF2U c; c.h = __float22bfloat162_rn(make_float2(x, y));
  return c.u;
}

// ---------------- setup kernels ----------------

__global__ __launch_bounds__(256) void k_zero(int* p, int n) {
  int i = blockIdx.x * 256 + threadIdx.x;
  if (i < n) p[i] = 0;
}

__global__ __launch_bounds__(256) void k_hist(const int* __restrict__ ei,
                                              const int* __restrict__ et,
                                              int* __restrict__ hist) {
  int e = blockIdx.x * 256 + threadIdx.x;   // grid covers E exactly
  int tgt = ei[N_EDGES + e];
  int r   = et[e];
  int key = ((tgt >> 4) << 8) | (r << 4) | (tgt & 15);
  atomicAdd(&hist[key], 1);
}

__global__ __launch_bounds__(256) void k_btot(const int* __restrict__ hist,
                                              int* __restrict__ totals) {
  __shared__ int s[256];
  int t = threadIdx.x, b = blockIdx.x;
  int sum = 0;
  for (int j = 0; j < 4; ++j) {
    int idx = b * 1024 + j * 256 + t;
    sum += (idx < N_BINS) ? hist[idx] : 0;
  }
  s[t] = sum; __syncthreads();
  for (int ofs = 128; ofs > 0; ofs >>= 1) {
    if (t < ofs) s[t] += s[t + ofs];
    __syncthreads();
  }
  if (t == 0) totals[b] = s[0];
}

__global__ __launch_bounds__(1024) void k_scan_totals(int* totals, int* off) {
  __shared__ int s[1024];
  int t = threadIdx.x;
  int v = (t < N_SCANBLK) ? totals[t] : 0;
  s[t] = v; __syncthreads();
  for (int ofs = 1; ofs < 1024; ofs <<= 1) {
    int x = (t >= ofs) ? s[t - ofs] : 0;
    __syncthreads();
    s[t] += x;
    __syncthreads();
  }
  if (t < N_SCANBLK) totals[t] = s[t] - v;   // exclusive scan of block totals
  if (t == 0) off[N_BINS] = N_EDGES;
}

__global__ __launch_bounds__(1024) void k_scan_within(int* __restrict__ hist /* becomes off in place */,
                                                      const int* __restrict__ totals,
                                                      int* __restrict__ cursors) {
  __shared__ int s[1024];
  int t = threadIdx.x, blk = blockIdx.x;
  int b = blk * 1024 + t;
  int v = (b < N_BINS) ? hist[b] : 0;
  s[t] = v; __syncthreads();
  for (int ofs = 1; ofs < 1024; ofs <<= 1) {
    int x = (t >= ofs) ? s[t - ofs] : 0;
    __syncthreads();
    s[t] += x;
    __syncthreads();
  }
  if (b < N_BINS) {
    int e = totals[blk] + s[t] - v;
    hist[b] = e;        // exclusive global offset
    cursors[b] = e;
  }
}

__global__ __launch_bounds__(256) void k_sort(const int* __restrict__ ei,
                                              const int* __restrict__ et,
                                              int* __restrict__ cursors,
                                              int* __restrict__ payload) {
  int e = blockIdx.x * 256 + threadIdx.x;
  int src = ei[e];
  int tgt = ei[N_EDGES + e];
  int r   = et[e];
  int key = ((tgt >> 4) << 8) | (r << 4) | (tgt & 15);
  int pos = atomicAdd(&cursors[key], 1);
  payload[pos] = (src << 4) | (tgt & 15);
}

// Bs: fragment-ordered B. Per layer: frag = ((r*4+kk)*8+cb), r in 0..16
// (16 = root), kk = 32-k chunk, cb = 16-col block. Within frag: 64 lanes x
// 8 bf16 (lane n = col cb*16+(lane&15), k = kk*32 + (lane>>4)*8 + j).
// A wave's B-frag load is 64x16B contiguous -> perfectly coalesced.
__global__ __launch_bounds__(256) void k_bt(const float* __restrict__ W,
                                            const float* __restrict__ root,
                                            ushort_t* __restrict__ Bs) {
  int idx = blockIdx.x * 256 + threadIdx.x;    // 3*BS_LAYER exact
  int l    = idx / BS_LAYER;
  int rem  = idx - l * BS_LAYER;
  int frag = rem >> 9;
  int wi   = rem & 511;
  int lane = wi >> 3;
  int j    = wi & 7;
  int cb   = frag & 7;
  int kk   = (frag >> 3) & 3;
  int r    = frag >> 5;                         // 0..16
  int col  = cb * 16 + (lane & 15);
  int d    = kk * 32 + (lane >> 4) * 8 + j;
  float v;
  if (r < 16) v = W[((size_t)(l * N_REL + r) * HID + d) * HID + col];
  else        v = root[((size_t)l * HID + d) * HID + col];
  __hip_bfloat16 h = __float2bfloat16(v);
  union { __hip_bfloat16 h; ushort_t u; } c; c.h = h;
  Bs[idx] = c.u;
}

// xh = bf16(x)  (layer-0 input conversion only; relu fused in k_main epilogue)
__global__ __launch_bounds__(256) void k_xh(const float* __restrict__ xin,
                                            ushort_t* __restrict__ xh) {
  int i = blockIdx.x * 256 + threadIdx.x;      // grid = N*H/4 exact
  float4 v = ((const float4*)xin)[i];
  uint2 u;
  u.x = pack_bf16_2(v.x, v.y);
  u.y = pack_bf16_2(v.z, v.w);
  ((uint2*)xh)[i] = u;
}

// ---------------- fused per-layer kernel ----------------
// M=32: block = 2 node-tiles (tile0, tile0+1). 4 waves; wave w privately owns
// relations {w, 4+w, 8+w, 12+w} (one per step) across ALL 128 output cols
// (8 C-frag pairs), accumulating partial C in regs. NO barriers in the
// K-loop: each wave gathers into its PRIVATE LDS agg slice and MFMAs only
// its own slice. vmcnt-legal pipeline per step:
//   consume G(s) [waits only gathers; B(s) older=arrived, younger loads fly]
//   flush bf16 agg -> issue G(s+1) -> MFMA(s) [B regs + LDS A: no vmem wait]
//   -> issue B(s+1) [reuses dead B regs]
// Root = 5th step: K=128 split 4 ways across waves (kk=wave), A from global.
// Epilogue: one LDS reduction of the 4 partial C's + bias (+relu), store.

#define AG_STRIDE 136   // ushorts/row: 272 B, 16-B aligned

__global__ __launch_bounds__(256, 2) void k_main(const ushort_t* __restrict__ xh,
                                                 ushort_t* __restrict__ xh_out,
                                                 float* __restrict__ fout,
                                                 const ushort_t* __restrict__ Bs,
                                                 const float* __restrict__ bias,
                                                 const int* __restrict__ off,
                                                 const int* __restrict__ payload,
                                                 int write_f32) {
  __shared__ char smem[65536];   // agg (34.8 KB) then reused as reduction (64 KB)

  const int tile0 = blockIdx.x * 2;
  const int tid   = threadIdx.x;
  const int wave  = tid >> 6;
  const int lane  = tid & 63;
  const int m16   = lane & 15;
  const int q     = lane >> 4;

  ushort_t* aggw = (ushort_t*)smem + wave * (2 * 16 * AG_STRIDE);
  const unsigned* xh32 = (const unsigned*)xh;

  f32x4 acc0[8], acc1[8];
#pragma unroll
  for (int cb = 0; cb < 8; ++cb) {
    acc0[cb] = (f32x4){0.f, 0.f, 0.f, 0.f};
    acc1[cb] = (f32x4){0.f, 0.f, 0.f, 0.f};
  }

  // ---- run bounds for all 4 steps x 2 tiles via one lane-parallel load ----
  int ebv = 0;
  {
    int l2 = lane & 15;
    int s2 = l2 >> 2, t2 = (l2 >> 1) & 1, h2 = l2 & 1;
    int bin = (tile0 + t2) * 256 + ((s2 * 4 + wave) << 4) + (h2 << 4);
    bin = bin > N_BINS ? N_BINS : bin;     // virtual tile -> empty run
    if (lane < 16) ebv = off[bin];
  }
  int e0g[4][2], e1g[4][2];
#pragma unroll
  for (int s2 = 0; s2 < 4; ++s2) {
#pragma unroll
    for (int t2 = 0; t2 < 2; ++t2) {
      e0g[s2][t2] = __builtin_amdgcn_readlane(ebv, s2 * 4 + t2 * 2);
      e1g[s2][t2] = __builtin_amdgcn_readlane(ebv, s2 * 4 + t2 * 2 + 1);
    }
  }

  short8 Breg[4][8];
  int sp0[16], sp1[16];
  unsigned xr0[16], xr1[16];
  int pv0, pv1;

#define LOAD_PV(S)                                                            \
  {                                                                           \
    int i0 = e0g[S][0] + lane; i0 = i0 < N_EDGES ? i0 : N_EDGES - 1;          \
    int i1 = e0g[S][1] + lane; i1 = i1 < N_EDGES ? i1 : N_EDGES - 1;          \
    pv0 = payload[i0]; pv1 = payload[i1];                                     \
  }

#define PREFETCH_G(PV, SPP, XRP)                                              \
  _Pragma("unroll")                                                           \
  for (int k = 0; k < 16; ++k) {                                              \
    SPP[k] = __builtin_amdgcn_readlane(PV, k);                                \
    XRP[k] = xh32[(SPP[k] >> 4) * 64 + lane];                                 \
  }

#define LOAD_B(REL)                                                           \
  _Pragma("unroll")                                                           \
  for (int kk = 0; kk < 4; ++kk)                                              \
    _Pragma("unroll")                                                         \
    for (int cb = 0; cb < 8; ++cb)                                            \
      Breg[kk][cb] = *(const short8*)(Bs + (size_t)(((((REL)*4 + kk) << 3) + cb) << 9) + lane * 8);

#define FLUSH(RB)                                                             \
  if (mcur >= 0) {                                                            \
    float sc = 1.0f / (float)ecnt;                                            \
    *(unsigned*)(aggw + ((RB) + mcur) * AG_STRIDE + lane * 2) =               \
        pack_bf16_2(a0 * sc, a1 * sc);                                        \
  }

#define CONSUME(SP, X, RB)                                                    \
  {                                                                           \
    int mk = (SP) & 15;                                                       \
    if (mk != mcur) { FLUSH(RB); mcur = mk; a0 = 0.f; a1 = 0.f; ecnt = 0; }   \
    a0 += __uint_as_float((X) << 16);                                         \
    a1 += __uint_as_float((X) & 0xffff0000u);                                 \
    ecnt++;                                                                   \
  }

#define RUN_CONSUME(E0, E1, PV, SPP, XRP, RB)                                 \
  {                                                                           \
    int cnt = (E1) - (E0);                                                    \
    int mcur = -1, ecnt = 0;                                                  \
    float a0 = 0.f, a1 = 0.f;                                                 \
    int n0 = cnt < 16 ? cnt : 16;                                             \
    _Pragma("unroll")                                                         \
    for (int k = 0; k < 16; ++k)                                              \
      if (k < n0) { CONSUME(SPP[k], XRP[k], RB); }                            \
    int lim = cnt < 64 ? cnt : 64;                                            \
    for (int j = 16; j < lim; j += 16) {                                      \
      int kn = lim - j; kn = kn < 16 ? kn : 16;                               \
      int sp2[16]; unsigned x2[16];                                           \
      _Pragma("unroll")                                                       \
      for (int k = 0; k < 16; ++k)                                            \
        if (k < kn) sp2[k] = __builtin_amdgcn_readlane(PV, j + k);            \
      _Pragma("unroll")                                                       \
      for (int k = 0; k < 16; ++k)                                            \
        if (k < kn) x2[k] = xh32[(sp2[k] >> 4) * 64 + lane];                  \
      _Pragma("unroll")                                                       \
      for (int k = 0; k < 16; ++k)                                            \
        if (k < kn) { CONSUME(sp2[k], x2[k], RB); }                           \
    }                                                                         \
    for (int c0 = (E0) + 64; c0 < (E1); c0 += 64) {                           \
      int nb = (E1) - c0; nb = nb < 64 ? nb : 64;                             \
      int ii = c0 + lane; ii = ii < (E1) ? ii : (E1) - 1;                     \
      int pvx = payload[ii];                                                  \
      for (int j = 0; j < nb; j += 16) {                                      \
        int kn = nb - j; kn = kn < 16 ? kn : 16;                              \
        int sp2[16]; unsigned x2[16];                                         \
        _Pragma("unroll")                                                     \
        for (int k = 0; k < 16; ++k)                                          \
          if (k < kn) sp2[k] = __builtin_amdgcn_readlane(pvx, j + k);         \
        _Pragma("unroll")                                                     \
        for (int k = 0; k < 16; ++k)                                          \
          if (k < kn) x2[k] = xh32[(sp2[k] >> 4) * 64 + lane];                \
        _Pragma("unroll")                                                     \
        for (int k = 0; k < 16; ++k)                                          \
          if (k < kn) { CONSUME(sp2[k], x2[k], RB); }                         \
      }                                                                       \
    }                                                                         \
    FLUSH(RB);                                                                \
  }

  // ---- prologue: pv(0), G(0), B(0)  (G before B so consume(0) drains only once)
  LOAD_PV(0);
  PREFETCH_G(pv0, sp0, xr0);
  PREFETCH_G(pv1, sp1, xr1);
  LOAD_B(wave);

  for (int s = 0; s < 4; ++s) {
    // zero my 32x128 agg region: 8 x ds_write_b128 (4 rows per store)
    {
      short8 z = {0, 0, 0, 0, 0, 0, 0, 0};
#pragma unroll
      for (int i = 0; i < 8; ++i) {
        int row = i * 4 + (lane >> 4);
        *(short8*)(aggw + row * AG_STRIDE + (lane & 15) * 8) = z;
      }
    }

    // consume this step's gathers (waits only on G(s); B(s+0) already here)
    RUN_CONSUME(e0g[s][0], e1g[s][0], pv0, sp0, xr0, 0);
    RUN_CONSUME(e0g[s][1], e1g[s][1], pv1, sp1, xr1, 16);

    // issue next step's gathers BEFORE MFMA so they fly under it
    if (s < 3) {
      LOAD_PV(s + 1);
      PREFETCH_G(pv0, sp0, xr0);
      PREFETCH_G(pv1, sp1, xr1);
    }

    // MFMA step s: LDS A (own slice) x B regs — no vmem waits
#pragma unroll
    for (int kk = 0; kk < 4; ++kk) {
      short8 a0 = *(const short8*)(aggw + m16 * AG_STRIDE + kk * 32 + q * 8);
      short8 a1 = *(const short8*)(aggw + (16 + m16) * AG_STRIDE + kk * 32 + q * 8);
#pragma unroll
      for (int cb = 0; cb < 8; ++cb) {
        acc0[cb] = __builtin_amdgcn_mfma_f32_16x16x32_bf16(a0, Breg[kk][cb], acc0[cb], 0, 0, 0);
        acc1[cb] = __builtin_amdgcn_mfma_f32_16x16x32_bf16(a1, Breg[kk][cb], acc1[cb], 0, 0, 0);
      }
    }

    // B for next step (reuses dead B regs); root frags after last step
    if (s < 3) { LOAD_B((s + 1) * 4 + wave); }
  }

  // ---- root: K=128 split across waves (this wave: k in wave*32..+32) ----
  {
    short8 br[8];
#pragma unroll
    for (int cb = 0; cb < 8; ++cb)
      br[cb] = *(const short8*)(Bs + (size_t)((((16 * 4 + wave) << 3) + cb) << 9) + lane * 8);
    short8 ra0 = *(const short8*)(xh + (size_t)(tile0 * 16 + m16) * HID + wave * 32 + q * 8);
    short8 ra1 = *(const short8*)(xh + (size_t)(tile0 * 16 + 16 + m16) * HID + wave * 32 + q * 8);
#pragma unroll
    for (int cb = 0; cb < 8; ++cb) {
      acc0[cb] = __builtin_amdgcn_mfma_f32_16x16x32_bf16(ra0, br[cb], acc0[cb], 0, 0, 0);
      acc1[cb] = __builtin_amdgcn_mfma_f32_16x16x32_bf16(ra1, br[cb], acc1[cb], 0, 0, 0);
    }
  }

  // ---- reduction: sum the 4 waves' partial C in LDS, + bias (+relu), store
  __syncthreads();
  {
    float* red = (float*)smem;   // [wave][32][128]
    float* myr = red + wave * 4096;
#pragma unroll
    for (int t = 0; t < 2; ++t)
#pragma unroll
      for (int cb = 0; cb < 8; ++cb) {
        f32x4 v = t ? acc1[cb] : acc0[cb];
#pragma unroll
        for (int rg = 0; rg < 4; ++rg)
          myr[(t * 16 + q * 4 + rg) * HID + cb * 16 + m16] = v[rg];
      }
  }
  __syncthreads();
  {
    const float* red = (const float*)smem;
    int row = tid >> 3;               // 0..31
    int cg  = (tid & 7) * 16;         // col group base
    int g   = blockIdx.x * 32 + row;  // global node row
    if (g < N_NODES) {
#pragma unroll
      for (int c4 = 0; c4 < 4; ++c4) {
        int col = cg + c4 * 4;
        float4 v = *(const float4*)&red[row * HID + col];
        const float4 v1 = *(const float4*)&red[4096 + row * HID + col];
        const float4 v2 = *(const float4*)&red[8192 + row * HID + col];
        const float4 v3 = *(const float4*)&red[12288 + row * HID + col];
        float4 bv = *(const float4*)(bias + col);
        v.x += v1.x + v2.x + v3.x + bv.x;
        v.y += v1.y + v2.y + v3.y + bv.y;
        v.z += v1.z + v2.z + v3.z + bv.z;
        v.w += v1.w + v2.w + v3.w + bv.w;
        if (write_f32) {
          *(float4*)(fout + (size_t)g * HID + col) = v;
        } else {
          v.x = fmaxf(v.x, 0.f); v.y = fmaxf(v.y, 0.f);
          v.z = fmaxf(v.z, 0.f); v.w = fmaxf(v.w, 0.f);
          uint2 u;
          u.x = pack_bf16_2(v.x, v.y);
          u.y = pack_bf16_2(v.z, v.w);
          *(uint2*)(xh_out + (size_t)g * HID + col) = u;
        }
      }
    }
  }
#undef RUN_CONSUME
#undef CONSUME
#undef FLUSH
#undef LOAD_B
#undef PREFETCH_G
#undef LOAD_PV
}

// ---------------- host ----------------

extern "C" void kernel_launch(void* const* d_in, const int* in_sizes, int n_in,
                              void* d_out, int out_size, void* d_ws, size_t ws_size,
                              hipStream_t stream) {
  const int*   ei        = (const int*)d_in[0];     // (2, E) int32
  const int*   et        = (const int*)d_in[1];     // (E,)   int32
  const float* node_init = (const float*)d_in[2];   // (N, H) f32
  const float* W         = (const float*)d_in[3];   // (3, 16, H, H) f32
  const float* root      = (const float*)d_in[4];   // (3, H, H) f32
  const float* bias      = (const float*)d_in[5];   // (3, H) f32
  float* outp = (float*)d_out;

  // workspace carving (256-B aligned)
  char* ws = (char*)d_ws;
  size_t o = 0;
  auto carve = [&](size_t bytes) { char* p = ws + o; o = (o + bytes + 255) & ~(size_t)255; return p; };
  ushort_t* xh_a    = (ushort_t*)carve((size_t)N_NODES * HID * 2);        // 12.8 MB
  ushort_t* xh_b    = (ushort_t*)carve((size_t)N_NODES * HID * 2);        // 12.8 MB
  int*      payload = (int*)     carve((size_t)N_EDGES * 4);              // 6.4 MB
  int*      off     = (int*)     carve((size_t)(N_BINS + 1) * 4);         // 3.2 MB (hist -> offsets in place)
  int*      cursors = (int*)     carve((size_t)N_BINS * 4);               // 3.2 MB
  int*      totals  = (int*)     carve((size_t)N_SCANBLK * 4);
  ushort_t* Bs      = (ushort_t*)carve((size_t)3 * BS_LAYER * 2);         // 1.67 MB
  (void)ws_size; (void)n_in; (void)in_sizes; (void)out_size;

  // ---- once-per-launch setup: counting sort by (tile, rel, node_local) + Bs ----
  hipLaunchKernelGGL(k_zero,        dim3(N_BINS / 256), dim3(256), 0, stream, off, N_BINS);
  hipLaunchKernelGGL(k_hist,        dim3(N_EDGES / 256), dim3(256), 0, stream, ei, et, off);
  hipLaunchKernelGGL(k_btot,        dim3(N_SCANBLK), dim3(256), 0, stream, off, totals);
  hipLaunchKernelGGL(k_scan_totals, dim3(1), dim3(1024), 0, stream, totals, off);
  hipLaunchKernelGGL(k_scan_within, dim3(N_SCANBLK), dim3(1024), 0, stream, off, totals, cursors);
  hipLaunchKernelGGL(k_sort,        dim3(N_EDGES / 256), dim3(256), 0, stream, ei, et, cursors, payload);
  hipLaunchKernelGGL(k_bt,          dim3(3 * BS_LAYER / 256), dim3(256), 0, stream, W, root, Bs);

  // layer-0 input -> bf16
  hipLaunchKernelGGL(k_xh, dim3(N_NODES * HID / 4 / 256), dim3(256), 0, stream,
                     node_init, xh_a);

  // ---- 3 layers, bf16 ping-pong; relu fused into epilogue of layers 0,1 ----
  hipLaunchKernelGGL(k_main, dim3(N_MBLK), dim3(256), 0, stream,
                     xh_a, xh_b, (float*)nullptr,
                     Bs + (size_t)0 * BS_LAYER, bias + 0 * HID, off, payload, 0);
  hipLaunchKernelGGL(k_main, dim3(N_MBLK), dim3(256), 0, stream,
                     xh_b, xh_a, (float*)nullptr,
                     Bs + (size_t)1 * BS_LAYER, bias + 1 * HID, off, payload, 0);
  hipLaunchKernelGGL(k_main, dim3(N_MBLK), dim3(256), 0, stream,
                     xh_a, (ushort_t*)nullptr, outp,
                     Bs + (size_t)2 * BS_LAYER, bias + 2 * HID, off, payload, 1);
}

// Round 6
// 611.340 us; speedup vs baseline: 2.9282x; 2.9282x over previous
//
#include <hip/hip_runtime.h>
#include <hip/hip_bf16.h>

#define N_NODES   50000
#define N_REL     16
#define HID       128
#define N_EDGES   1600000
#define N_TILES   3125          // N_NODES/16
#define N_BINS    800000        // fine bins (tile, rel, m)
#define N_RUNS    50000         // (tile, rel) runs of 16 fine bins
#define N_SCANBLK 49            // ceil(N_RUNS/1024)
#define N_MBLK    1563          // ceil(3125/2): M=32 per block
#define PAYLOAD_CAP 2400064     // E + 50000*15 pad worst case + slack
#define BS_LAYER  278528        // (16 rel + root)*4kk*8cb frags * 512 ushorts
#define AG_STRIDE 136           // ushorts per agg row (272 B, 16-B aligned)

typedef unsigned short ushort_t;
typedef __attribute__((ext_vector_type(8))) short short8;
typedef __attribute__((ext_vector_type(4))) float f32x4;

union BF2U { __hip_bfloat162 h; unsigned u; };

__device__ __forceinline__ unsigned pack_bf16_2(float x, float y) {
  BF2U c; c.h = __float22bfloat162_rn(make_float2(x, y));
  return c.u;
}

// ---------------- setup kernels ----------------

__global__ __launch_bounds__(256) void k_zero(int* p, int n) {
  int i = blockIdx.x * 256 + threadIdx.x;
  if (i < n) p[i] = 0;
}

__global__ __launch_bounds__(256) void k_hist(const int* __restrict__ ei,
                                              const int* __restrict__ et,
                                              int* __restrict__ cnt) {
  int e = blockIdx.x * 256 + threadIdx.x;   // grid covers E exactly
  int tgt = ei[N_EDGES + e];
  int r   = et[e];
  int key = ((tgt >> 4) << 8) | (r << 4) | (tgt & 15);
  atomicAdd(&cnt[key], 1);
}

// per-run real total -> padded-to-16 total (into run_start array, pre-scan)
__global__ __launch_bounds__(256) void k_runpad(const int* __restrict__ cnt,
                                                int* __restrict__ padtot) {
  int r = blockIdx.x * 256 + threadIdx.x;
  if (r >= N_RUNS) return;
  const int4* c4 = (const int4*)(cnt + r * 16);
  int s = 0;
#pragma unroll
  for (int j = 0; j < 4; ++j) { int4 v = c4[j]; s += v.x + v.y + v.z + v.w; }
  padtot[r] = (s + 15) & ~15;
}

__global__ __launch_bounds__(256) void k_btot(const int* __restrict__ in,
                                              int* __restrict__ totals, int n) {
  __shared__ int s[256];
  int t = threadIdx.x, b = blockIdx.x;
  int sum = 0;
  for (int j = 0; j < 4; ++j) {
    int idx = b * 1024 + j * 256 + t;
    sum += (idx < n) ? in[idx] : 0;
  }
  s[t] = sum; __syncthreads();
  for (int ofs = 128; ofs > 0; ofs >>= 1) {
    if (t < ofs) s[t] += s[t + ofs];
    __syncthreads();
  }
  if (t == 0) totals[b] = s[0];
}

__global__ __launch_bounds__(1024) void k_scan_totals(int* totals, int* endp, int nblk) {
  __shared__ int s[1024];
  int t = threadIdx.x;
  int v = (t < nblk) ? totals[t] : 0;
  s[t] = v; __syncthreads();
  for (int ofs = 1; ofs < 1024; ofs <<= 1) {
    int x = (t >= ofs) ? s[t - ofs] : 0;
    __syncthreads();
    s[t] += x;
    __syncthreads();
  }
  if (t < nblk) totals[t] = s[t] - v;      // exclusive block offsets
  if (t == nblk - 1) *endp = s[t];         // grand total (padded edge count)
}

__global__ __launch_bounds__(1024) void k_scan_within(int* __restrict__ a,
                                                      const int* __restrict__ totals,
                                                      int n) {
  __shared__ int s[1024];
  int t = threadIdx.x, blk = blockIdx.x;
  int b = blk * 1024 + t;
  int v = (b < n) ? a[b] : 0;
  s[t] = v; __syncthreads();
  for (int ofs = 1; ofs < 1024; ofs <<= 1) {
    int x = (t >= ofs) ? s[t - ofs] : 0;
    __syncthreads();
    s[t] += x;
    __syncthreads();
  }
  if (b < n) a[b] = totals[blk] + s[t] - v;   // exclusive padded offsets
}

// fine-bin cursors within each run + dummy-fill the pad region
__global__ __launch_bounds__(256) void k_fineoff(const int* __restrict__ cnt,
                                                 const int* __restrict__ run_start,
                                                 int* __restrict__ cursors,
                                                 unsigned* __restrict__ payload) {
  int r = blockIdx.x * 256 + threadIdx.x;
  if (r >= N_RUNS) return;
  int base = run_start[r];
  int e1   = run_start[r + 1];
  int pfx = 0;
  for (int i = 0; i < 16; ++i) {
    cursors[r * 16 + i] = base + pfx;
    pfx += cnt[r * 16 + i];
  }
  const unsigned dummy = ((unsigned)N_NODES << 16) | (1u << 4) | 15u;
  for (int j = base + pfx; j < e1; ++j) payload[j] = dummy;  // m=15, zero row
}

// payload = src:31..16 | bin_cnt:15..4 | m:3..0
__global__ __launch_bounds__(256) void k_sort(const int* __restrict__ ei,
                                              const int* __restrict__ et,
                                              const int* __restrict__ cnt,
                                              int* __restrict__ cursors,
                                              unsigned* __restrict__ payload) {
  int e = blockIdx.x * 256 + threadIdx.x;
  int src = ei[e];
  int tgt = ei[N_EDGES + e];
  int r   = et[e];
  int key = ((tgt >> 4) << 8) | (r << 4) | (tgt & 15);
  int c = cnt[key]; c = c > 4095 ? 4095 : c;
  int pos = atomicAdd(&cursors[key], 1);
  payload[pos] = ((unsigned)src << 16) | ((unsigned)c << 4) | (unsigned)(tgt & 15);
}

// Bs fragment-ordered: frag = ((r*4+kk)*8+cb), r 0..16 (16=root); within frag
// 64 lanes x 8 bf16: lane = col cb*16+(lane&15), k = kk*32+(lane>>4)*8+j.
__global__ __launch_bounds__(256) void k_bt(const float* __restrict__ W,
                                            const float* __restrict__ root,
                                            ushort_t* __restrict__ Bs) {
  int idx = blockIdx.x * 256 + threadIdx.x;    // 3*BS_LAYER exact
  int l    = idx / BS_LAYER;
  int rem  = idx - l * BS_LAYER;
  int frag = rem >> 9;
  int wi   = rem & 511;
  int lane = wi >> 3;
  int j    = wi & 7;
  int cb   = frag & 7;
  int kk   = (frag >> 3) & 3;
  int r    = frag >> 5;                         // 0..16
  int col  = cb * 16 + (lane & 15);
  int d    = kk * 32 + (lane >> 4) * 8 + j;
  float v;
  if (r < 16) v = W[((size_t)(l * N_REL + r) * HID + d) * HID + col];
  else        v = root[((size_t)l * HID + d) * HID + col];
  __hip_bfloat16 h = __float2bfloat16(v);
  union { __hip_bfloat16 h; ushort_t u; } c; c.h = h;
  Bs[idx] = c.u;
}

__global__ __launch_bounds__(256) void k_xh(const float* __restrict__ xin,
                                            ushort_t* __restrict__ xh) {
  int i = blockIdx.x * 256 + threadIdx.x;      // grid = N*H/4 exact
  float4 v = ((const float4*)xin)[i];
  uint2 u;
  u.x = pack_bf16_2(v.x, v.y);
  u.y = pack_bf16_2(v.z, v.w);
  ((uint2*)xh)[i] = u;
}

// zero the dummy node row (row N_NODES) of both ping-pong buffers
__global__ __launch_bounds__(256) void k_zrow(ushort_t* xa, ushort_t* xb) {
  int t = threadIdx.x;
  if (t < 128) xa[(size_t)N_NODES * HID + t] = 0;
  else         xb[(size_t)N_NODES * HID + (t - 128)] = 0;
}

// ---------------- fused per-layer kernel: producer/consumer waves ----------
// Block = 32 nodes (2 tiles), 4 waves. Waves 0,1 = PRODUCERS: gather rel
// 2s+p per step s (runs padded to x16, cnt in payload -> no guards, no off
// reads), register-RLE, bf16 flush into double-buffered LDS agg
// [buf2][rp2][32][AG_STRIDE]. Their vmem stream contains ONLY payload/gather
// loads -> per-wave in-order vmcnt never forces cross-stream drains; next
// step's first batches are issued before each barrier so they fly under the
// consumers' MFMA. Waves 2,3 = CONSUMERS: per step MFMA rels {2s,2s+1} from
// agg[s&1] x 64 own cols, B frags (1 KB coalesced) from Bs; + root + epilogue.

__global__ __launch_bounds__(256, 3) void k_main(const ushort_t* __restrict__ xh,
                                                 ushort_t* __restrict__ xh_out,
                                                 float* __restrict__ fout,
                                                 const ushort_t* __restrict__ Bs,
                                                 const float* __restrict__ bias,
                                                 const int* __restrict__ run_start,
                                                 const unsigned* __restrict__ payload,
                                                 int write_f32) {
  __shared__ alignas(16) ushort_t agg[2][2][32][AG_STRIDE];   // 34.8 KB

  const int tile0 = blockIdx.x * 2;
  const int tid   = threadIdx.x;
  const int wave  = tid >> 6;
  const int lane  = tid & 63;
  const int m16   = lane & 15;
  const int q     = lane >> 4;
  const unsigned* xh32 = (const unsigned*)xh;

  if (wave < 2) {
    // ======================= PRODUCER =======================
    const int p = wave;
    // run bounds, 32 values lane-parallel: lane = s*4 + t*2 + h
    int ebv = 0;
    {
      int s8 = lane >> 2, t2 = (lane >> 1) & 1, h = lane & 1;
      int tt = tile0 + t2;
      int idx = (tt < N_TILES) ? (tt * 16 + s8 * 2 + p + h) : N_RUNS;
      if (lane < 32) ebv = run_start[idx];
    }
    // payload chunks for all 8 steps x 2 tiles (runs <=64 a.s.)
    int pv[8][2];
#pragma unroll
    for (int s = 0; s < 8; ++s)
#pragma unroll
      for (int t = 0; t < 2; ++t) {
        int e0 = __builtin_amdgcn_readlane(ebv, s * 4 + t * 2);
        pv[s][t] = (int)payload[e0 + lane];
      }

#define ISSUE16(DST, PV, JB)                                                  \
    _Pragma("unroll")                                                         \
    for (int k1 = 0; k1 < 16; ++k1) {                                         \
      unsigned spq = (unsigned)__builtin_amdgcn_readlane(PV, (JB) + k1);      \
      DST[k1] = xh32[(spq >> 16) * 64 + lane];                                \
    }

#define FLUSHM(TB, BUF)                                                       \
    if (mcur >= 0) {                                                          \
      float sc = __builtin_amdgcn_rcpf((float)scnt);                          \
      *(unsigned*)&agg[BUF][p][(TB) + mcur][lane * 2] =                       \
          pack_bf16_2(a0 * sc, a1 * sc);                                      \
    }

#define CONSUME1(SPK, XV, TB, BUF)                                            \
    {                                                                         \
      int mk = (int)((SPK) & 15u);                                            \
      if (mk != mcur) {                                                       \
        FLUSHM(TB, BUF);                                                      \
        mcur = mk; scnt = (int)(((SPK) >> 4) & 4095u);                        \
        a0 = 0.f; a1 = 0.f;                                                   \
      }                                                                       \
      a0 += __uint_as_float((XV) << 16);                                      \
      a1 += __uint_as_float((XV) & 0xffff0000u);                              \
    }

#define CONS16(PV, JB, SLOT, TB, BUF)                                         \
    _Pragma("unroll")                                                         \
    for (int k2 = 0; k2 < 16; ++k2) {                                         \
      unsigned spk = (unsigned)__builtin_amdgcn_readlane(PV, (JB) + k2);      \
      CONSUME1(spk, SLOT[k2], TB, BUF);                                       \
    }

#define RUNC(E0, E1, PV, S0, S1a, S1b, TB, BUF)                               \
    {                                                                         \
      int cnt = (E1) - (E0);                                                  \
      int mcur = -1, scnt = 1;                                                \
      float a0 = 0.f, a1 = 0.f;                                               \
      if (cnt > 0) {                                                          \
        if (cnt > 16) { ISSUE16(S1a, PV, 16); }                               \
        CONS16(PV, 0, S0, TB, BUF);                                           \
        if (cnt > 16) {                                                       \
          if (cnt > 32) { ISSUE16(S1b, PV, 32); }                             \
          CONS16(PV, 16, S1a, TB, BUF);                                       \
          if (cnt > 32) {                                                     \
            if (cnt > 48) { ISSUE16(S1a, PV, 48); }                           \
            CONS16(PV, 32, S1b, TB, BUF);                                     \
            if (cnt > 48) { CONS16(PV, 48, S1a, TB, BUF); }                   \
          }                                                                   \
        }                                                                     \
        for (int c0 = (E0) + 64; c0 < (E1); c0 += 16) { /* rare */            \
          int pvx = (int)payload[c0 + lane];                                  \
          unsigned xv[16];                                                    \
          ISSUE16(xv, pvx, 0);                                                \
          CONS16(pvx, 0, xv, TB, BUF);                                        \
        }                                                                     \
        FLUSHM(TB, BUF);                                                      \
      }                                                                       \
    }

    unsigned xqA[16], xqB[16], xqC[16], xqD[16];
    ISSUE16(xqA, pv[0][0], 0);
    ISSUE16(xqB, pv[0][1], 0);

#pragma unroll
    for (int s = 0; s < 8; ++s) {
      const int buf = s & 1;
      // zero my slice (32 rows x 128 dims): 8 ds_write_b128/lane
      {
        short8 z = {0, 0, 0, 0, 0, 0, 0, 0};
#pragma unroll
        for (int i = 0; i < 8; ++i)
          *(short8*)&agg[buf][p][i * 4 + q][m16 * 8] = z;
      }
      int e00 = __builtin_amdgcn_readlane(ebv, s * 4 + 0);
      int e01 = __builtin_amdgcn_readlane(ebv, s * 4 + 1);
      int e10 = __builtin_amdgcn_readlane(ebv, s * 4 + 2);
      int e11 = __builtin_amdgcn_readlane(ebv, s * 4 + 3);
      RUNC(e00, e01, pv[s][0], xqA, xqC, xqD, 0, buf);
      RUNC(e10, e11, pv[s][1], xqB, xqC, xqD, 16, buf);
      if (s < 7) {                        // next step's first batches fly
        ISSUE16(xqA, pv[s + 1][0], 0);    // under consumers' MFMA + barrier
        ISSUE16(xqB, pv[s + 1][1], 0);
      }
      __syncthreads();                    // barrier s: fill s visible
    }
#undef RUNC
#undef CONS16
#undef CONSUME1
#undef FLUSHM
#undef ISSUE16
    return;                               // producers exit; 8 barriers done
  }

  // ======================= CONSUMER =======================
  const int c = wave - 2;                 // owns cols c*64 .. c*64+64
  f32x4 acc[2][4];
#pragma unroll
  for (int t = 0; t < 2; ++t)
#pragma unroll
    for (int i = 0; i < 4; ++i) acc[t][i] = (f32x4){0.f, 0.f, 0.f, 0.f};

  for (int s = 0; s < 8; ++s) {
    __syncthreads();                      // barrier s: agg[s&1] ready
#pragma unroll
    for (int rp = 0; rp < 2; ++rp) {
      int rel = s * 2 + rp;
      short8 Bf[4][4];
#pragma unroll
      for (int kk = 0; kk < 4; ++kk)
#pragma unroll
        for (int i = 0; i < 4; ++i)
          Bf[kk][i] = *(const short8*)(Bs +
              ((size_t)((rel * 4 + kk) * 8 + (c * 4 + i)) << 9) + lane * 8);
#pragma unroll
      for (int kk = 0; kk < 4; ++kk) {
        short8 A0 = *(const short8*)&agg[s & 1][rp][m16][kk * 32 + q * 8];
        short8 A1 = *(const short8*)&agg[s & 1][rp][16 + m16][kk * 32 + q * 8];
#pragma unroll
        for (int i = 0; i < 4; ++i) {
          acc[0][i] = __builtin_amdgcn_mfma_f32_16x16x32_bf16(A0, Bf[kk][i], acc[0][i], 0, 0, 0);
          acc[1][i] = __builtin_amdgcn_mfma_f32_16x16x32_bf16(A1, Bf[kk][i], acc[1][i], 0, 0, 0);
        }
      }
    }
  }

  // ---- root (rel index 16): A from global xh rows of this block ----
  {
    short8 Bf[4][4];
#pragma unroll
    for (int kk = 0; kk < 4; ++kk)
#pragma unroll
      for (int i = 0; i < 4; ++i)
        Bf[kk][i] = *(const short8*)(Bs +
            ((size_t)((16 * 4 + kk) * 8 + (c * 4 + i)) << 9) + lane * 8);
    int r0 = tile0 * 16 + m16;      if (r0 > N_NODES) r0 = N_NODES;
    int r1 = tile0 * 16 + 16 + m16; if (r1 > N_NODES) r1 = N_NODES;
#pragma unroll
    for (int kk = 0; kk < 4; ++kk) {
      short8 A0 = *(const short8*)(xh + (size_t)r0 * HID + kk * 32 + q * 8);
      short8 A1 = *(const short8*)(xh + (size_t)r1 * HID + kk * 32 + q * 8);
#pragma unroll
      for (int i = 0; i < 4; ++i) {
        acc[0][i] = __builtin_amdgcn_mfma_f32_16x16x32_bf16(A0, Bf[kk][i], acc[0][i], 0, 0, 0);
        acc[1][i] = __builtin_amdgcn_mfma_f32_16x16x32_bf16(A1, Bf[kk][i], acc[1][i], 0, 0, 0);
      }
    }
  }

  // ---- epilogue: bias (+relu+bf16 or f32). C/D: col=lane&15, row=q*4+reg
  float bvv[4];
#pragma unroll
  for (int i = 0; i < 4; ++i) bvv[i] = bias[(c * 4 + i) * 16 + m16];
  int rbase = tile0 * 16 + q * 4;
#pragma unroll
  for (int t = 0; t < 2; ++t)
#pragma unroll
    for (int rg = 0; rg < 4; ++rg) {
      int row = rbase + t * 16 + rg;
      if (row < N_NODES) {
#pragma unroll
        for (int i = 0; i < 4; ++i) {
          float v = acc[t][i][rg] + bvv[i];
          int col = (c * 4 + i) * 16 + m16;
          if (write_f32) {
            fout[(size_t)row * HID + col] = v;
          } else {
            v = fmaxf(v, 0.f);
            union { __hip_bfloat16 h; ushort_t u; } cv;
            cv.h = __float2bfloat16(v);
            xh_out[(size_t)row * HID + col] = cv.u;
          }
        }
      }
    }
}

// ---------------- host ----------------

extern "C" void kernel_launch(void* const* d_in, const int* in_sizes, int n_in,
                              void* d_out, int out_size, void* d_ws, size_t ws_size,
                              hipStream_t stream) {
  const int*   ei        = (const int*)d_in[0];     // (2, E) int32
  const int*   et        = (const int*)d_in[1];     // (E,)   int32
  const float* node_init = (const float*)d_in[2];   // (N, H) f32
  const float* W         = (const float*)d_in[3];   // (3, 16, H, H) f32
  const float* root      = (const float*)d_in[4];   // (3, H, H) f32
  const float* bias      = (const float*)d_in[5];   // (3, H) f32
  float* outp = (float*)d_out;

  char* ws = (char*)d_ws;
  size_t o = 0;
  auto carve = [&](size_t bytes) { char* p = ws + o; o = (o + bytes + 255) & ~(size_t)255; return p; };
  ushort_t* xh_a      = (ushort_t*)carve((size_t)(N_NODES + 1) * HID * 2);   // +dummy row
  ushort_t* xh_b      = (ushort_t*)carve((size_t)(N_NODES + 1) * HID * 2);
  unsigned* payload   = (unsigned*)carve((size_t)PAYLOAD_CAP * 4);
  int*      cnt       = (int*)     carve((size_t)N_BINS * 4);
  int*      cursors   = (int*)     carve((size_t)N_BINS * 4);
  int*      run_start = (int*)     carve((size_t)(N_RUNS + 1) * 4);
  int*      totals    = (int*)     carve((size_t)N_SCANBLK * 4);
  ushort_t* Bs        = (ushort_t*)carve((size_t)3 * BS_LAYER * 2);
  (void)ws_size; (void)n_in; (void)in_sizes; (void)out_size;

  // ---- setup: padded counting sort by (tile, rel, m) + B swizzle ----
  hipLaunchKernelGGL(k_zero,        dim3(N_BINS / 256), dim3(256), 0, stream, cnt, N_BINS);
  hipLaunchKernelGGL(k_hist,        dim3(N_EDGES / 256), dim3(256), 0, stream, ei, et, cnt);
  hipLaunchKernelGGL(k_runpad,      dim3((N_RUNS + 255) / 256), dim3(256), 0, stream, cnt, run_start);
  hipLaunchKernelGGL(k_btot,        dim3(N_SCANBLK), dim3(256), 0, stream, run_start, totals, N_RUNS);
  hipLaunchKernelGGL(k_scan_totals, dim3(1), dim3(1024), 0, stream, totals, run_start + N_RUNS, N_SCANBLK);
  hipLaunchKernelGGL(k_scan_within, dim3(N_SCANBLK), dim3(1024), 0, stream, run_start, totals, N_RUNS);
  hipLaunchKernelGGL(k_fineoff,     dim3((N_RUNS + 255) / 256), dim3(256), 0, stream, cnt, run_start, cursors, payload);
  hipLaunchKernelGGL(k_sort,        dim3(N_EDGES / 256), dim3(256), 0, stream, ei, et, cnt, cursors, payload);
  hipLaunchKernelGGL(k_bt,          dim3(3 * BS_LAYER / 256), dim3(256), 0, stream, W, root, Bs);
  hipLaunchKernelGGL(k_xh,          dim3(N_NODES * HID / 4 / 256), dim3(256), 0, stream, node_init, xh_a);
  hipLaunchKernelGGL(k_zrow,        dim3(1), dim3(256), 0, stream, xh_a, xh_b);

  // ---- 3 layers, bf16 ping-pong; relu fused into epilogue of layers 0,1 ----
  hipLaunchKernelGGL(k_main, dim3(N_MBLK), dim3(256), 0, stream,
                     xh_a, xh_b, (float*)nullptr,
                     Bs + (size_t)0 * BS_LAYER, bias + 0 * HID, run_start, payload, 0);
  hipLaunchKernelGGL(k_main, dim3(N_MBLK), dim3(256), 0, stream,
                     xh_b, xh_a, (float*)nullptr,
                     Bs + (size_t)1 * BS_LAYER, bias + 1 * HID, run_start, payload, 0);
  hipLaunchKernelGGL(k_main, dim3(N_MBLK), dim3(256), 0, stream,
                     xh_a, (ushort_t*)nullptr, outp,
                     Bs + (size_t)2 * BS_LAYER, bias + 2 * HID, run_start, payload, 1);
}